// Round 11
// baseline (309.172 us; speedup 1.0000x reference)
//
#include <hip/hip_runtime.h>
#include <hip/hip_bf16.h>
#include <stdint.h>

typedef float f32x16 __attribute__((ext_vector_type(16)));
typedef int   i32x8  __attribute__((ext_vector_type(8)));

#define LOG2E 1.4426950408889634f
#define WSCALE 16.0f
#define AS1 __attribute__((address_space(1)))
#define AS3 __attribute__((address_space(3)))

// fp8 MX operand layout ("lane-contiguous tile-frag order", 32-row frags,
// 64-k tiles): panel of R rows (R=128 A / 256 B) stored as
//   [k-tile t (64 k)][frag f (32 rows)][lane l 0..63] x 32B
// lane chunk (f,l) holds row f*32+(l&31), k = t*64 + (l>>5)*32 + 0..31
// (bytes ascending k) — exactly one mfma_scale_f32_32x32x64_f8f6f4 A/B
// fragment per lane, loadable as ONE aligned i32x8 (2x ds_read_b128, no
// register assembly). Staging is a byte-identical sequential copy
// (base + tid*16). Same k-order as the r9/r10 absmax-0-verified layout.
// W pre-scaled x16; epilogue multiplies logits by 1/16. MX scales fixed at
// E8M0 1.0 (byte 127) == exact fp8 matmul.

// ---------------- f32 -> OCP e4m3 (RNE, clamp; verified r8-r10 absmax=0) ----
__device__ __forceinline__ uint32_t f32_to_e4m3(float x) {
    uint32_t ux = __float_as_uint(x);
    uint32_t s = (ux >> 24) & 0x80u;
    float a = __uint_as_float(ux & 0x7FFFFFFFu);
    if (a >= 448.0f) return s | 0x7Eu;
    int e = (int)((ux >> 23) & 0xFFu) - 127;
    if (e < -6) {
        int n = __float2int_rn(a * 512.0f);
        return s | (uint32_t)n;
    }
    uint32_t m = ux & 0x7FFFFFu;
    uint32_t r = (m + 0x7FFFFu + ((m >> 20) & 1u)) >> 20;
    if (r == 8u) { r = 0u; e += 1; }
    if (e > 8 || (e == 8 && r == 7u)) return s | 0x7Eu;
    return s | ((uint32_t)(e + 7) << 3) | r;
}

__device__ __forceinline__ uint32_t pack4_fp8v(float4 v, float sc) {
    return f32_to_e4m3(v.x * sc) | (f32_to_e4m3(v.y * sc) << 8) |
           (f32_to_e4m3(v.z * sc) << 16) | (f32_to_e4m3(v.w * sc) << 24);
}

__device__ __forceinline__ uint32_t pack4_fp8(const float* s, float sc) {
    return f32_to_e4m3(s[0] * sc) | (f32_to_e4m3(s[1] * sc) << 8) |
           (f32_to_e4m3(s[2] * sc) << 16) | (f32_to_e4m3(s[3] * sc) << 24);
}

__device__ __forceinline__ uint4 cvt16_fp8(const float* s, float sc) {
    uint4 r;
    r.x = pack4_fp8(s, sc);      r.y = pack4_fp8(s + 4, sc);
    r.z = pack4_fp8(s + 8, sc);  r.w = pack4_fp8(s + 12, sc);
    return r;
}

// ---------------- prep: build indices from batch_sizes ----------------
__global__ void prep_kernel(const int* __restrict__ bs, int T,
                            const int* __restrict__ sentences,
                            int* __restrict__ hdr, float* __restrict__ fhdr,
                            int* __restrict__ row_ctx, int* __restrict__ row_tok) {
    __shared__ int off[1025];
    if (threadIdx.x == 0) {
        int acc = 0; off[0] = 0;
        for (int t = 0; t < T; ++t) { acc += bs[t]; off[t + 1] = acc; }
    }
    __syncthreads();
    const int total = off[T];
    const int Nf = total - off[1];
    const int Nb = total - off[2];
    for (int t = 1; t < T; ++t) {
        int start = off[t] - off[1];
        int cnt = off[t + 1] - off[t];
        for (int p = threadIdx.x; p < cnt; p += blockDim.x) {
            row_ctx[start + p] = off[t - 1] + p;
            row_tok[start + p] = sentences[off[t] + p];
        }
    }
    for (int i = 1; i < T - 1; ++i) {
        int start = Nf + off[i + 1] - off[2];
        int cnt = off[i + 2] - off[i + 1];
        for (int p = threadIdx.x; p < cnt; p += blockDim.x) {
            row_ctx[start + p] = off[i + 1] + p;
            row_tok[start + p] = sentences[off[i] + p];
        }
    }
    if (threadIdx.x == 0) {
        hdr[0] = Nf + Nb;
        hdr[1] = Nf;
        int bs0 = off[1];
        int bsl = off[T] - off[T - 1];
        fhdr[0] = (float)(2 * total - bs0 - bsl);
    }
}

// ---------------- W f32 -> fp8 (x16), MX panels, LDS-staged transpose -------
// grid: (V/256)*8 blocks x 512 threads; block (p = bx>>3, f = bx&7) owns a
// 32-row stripe. Coalesced float4 reads; LDS write at frag-layout byte
// (l*32 + (kloc&31)); 128 threads dump the 2KB tile sequentially (verified
// r10: coalesced both sides).
__global__ void wconv_kernel(const float* __restrict__ W,
                             uint8_t* __restrict__ Wb, int K) {
    const int p = blockIdx.x >> 3, f = blockIdx.x & 7;
    __shared__ __align__(16) char tile[2048];
    char* panel = (char*)Wb + (size_t)p * ((size_t)K << 8);   // 256 rows * K B
    const int tid = threadIdx.x;
    const int rloc = tid >> 4;            // 0..31
    const int kloc = (tid & 15) << 2;     // 0..60, step 4
    const int l = rloc | (kloc & 32);     // lane = row-in-frag | k-group*32
    const int ldst = l * 32 + (kloc & 31);
    const float* src = W + (size_t)(p * 256 + f * 32 + rloc) * K + kloc;
    const int NT = K >> 6;
    for (int t = 0; t < NT; ++t) {
        const float4 v = *(const float4*)(src + t * 64);
        const uint32_t pk = pack4_fp8v(v, WSCALE);
        __syncthreads();                              // prev write-out done
        *(uint32_t*)(tile + ldst) = pk;
        __syncthreads();
        if (tid < 128)
            *(uint4*)(panel + (size_t)t * 16384 + f * 2048 + (tid << 4)) =
                *(const uint4*)(tile + (tid << 4));
    }
}

// ---------------- gather ctx rows -> fp8 128-row MX panels, zero S ----------
// grid: (Mcap/128)*4 blocks x 512 threads; block (p = bx>>2, f = bx&3)
__global__ void gather_kernel(const float* __restrict__ hs,
                              const int* __restrict__ row_ctx,
                              const int* __restrict__ hdr,
                              uint8_t* __restrict__ Hc,
                              float* __restrict__ S, int D2, int K) {
    const int p = blockIdx.x >> 2, f = blockIdx.x & 3;
    const int M = hdr[0], Nf = hdr[1];
    if (f == 0 && threadIdx.x < 128) S[p * 128 + threadIdx.x] = 0.f;
    char* panel = (char*)Hc + (size_t)p * ((size_t)K << 7);   // 128 rows * K B
    const int row0 = p * 128 + f * 32;
    const int nch = (K >> 6) << 7;   // 16B granules: (K/64 tiles) * 128
    for (int c = threadIdx.x; c < nch; c += 512) {
        const int t = c >> 7, r = c & 127;
        const int l = r >> 1, half = r & 1;
        const int row = row0 + (l & 31);
        char* d = panel + (size_t)t * 8192 + f * 2048 + l * 32 + half * 16;
        if (row >= M) {
            uint4 z; z.x = z.y = z.z = z.w = 0u;
            *(uint4*)d = z;
        } else {
            const int ctx = row_ctx[row];
            const int k = t * 64 + ((l >> 5) << 5) + half * 16;
            *(uint4*)d = cvt16_fp8(hs + (size_t)ctx * D2 + (row < Nf ? 0 : K) + k, 1.0f);
        }
    }
}

// ---------------- main 128x256 / BK=64 / 8-wave MX-fp8 GEMM + sum-exp -------
// r8/r10's proven schedule; static double-buffer (2x-unrolled loop) and
// single-load i32x8 fragments to cut codegen VALU.
__global__ __launch_bounds__(512, 4)
void gemm_lse(const uint8_t* __restrict__ A,
              const uint8_t* __restrict__ B,
              const float* __restrict__ fb,
              const float* __restrict__ bb,
              float* __restrict__ S,
              const int* __restrict__ hdr, int K, int MT) {
    const int M = hdr[0], Nf = hdr[1];

    // XCD-aware bijective swizzle (m204), bm-fastest (verified r2/r6/r8).
    const int nwg = gridDim.x, orig = blockIdx.x;
    const int q = nwg >> 3, rr = nwg & 7;
    const int xcd = orig & 7, i8 = orig >> 3;
    const int wgid = (xcd < rr ? xcd * (q + 1) : rr * (q + 1) + (xcd - rr) * q) + i8;
    const int bm = wgid % MT, bn = wgid / MT;
    if (bm * 128 >= M) return;

    __shared__ __align__(32) char lA[2][8192];     // BK=64 of A (128 rows)
    __shared__ __align__(32) char lB[2][16384];    // BK=64 of B (256 rows)

    const int tid = threadIdx.x, lane = tid & 63, wid = tid >> 6;
    const int wm = wid >> 2, wn = wid & 3;     // 2M x 4N waves, each 64x64 out

    f32x16 acc00 = (f32x16)0.f, acc01 = (f32x16)0.f;
    f32x16 acc10 = (f32x16)0.f, acc11 = (f32x16)0.f;

    const char* Ap = (const char*)A + (size_t)bm * ((size_t)K << 7);
    const char* Bp = (const char*)B + (size_t)bn * ((size_t)K << 8);
    const int sd = tid << 4;
    const int ao = ((wm * 2) << 11) + (lane << 5);   // + mf*2048
    const int bo = ((wn * 2) << 11) + (lane << 5);   // + nf*2048

#define GLDS(src, dst) __builtin_amdgcn_global_load_lds(                      \
        (const AS1 uint32_t*)(src), (AS3 uint32_t*)(dst), 16, 0, 0)

#define STAGE(buf, s) do {                                                    \
    GLDS(Ap + ((size_t)(s) << 13) + sd,        lA[buf] + sd);                 \
    GLDS(Bp + ((size_t)(s) << 14) + sd,        lB[buf] + sd);                 \
    GLDS(Bp + ((size_t)(s) << 14) + 8192 + sd, lB[buf] + 8192 + sd);          \
} while (0)

#define COMPUTE(buf) do {                                                     \
    const i32x8 a0 = *(const i32x8*)(lA[buf] + ao);                           \
    const i32x8 a1 = *(const i32x8*)(lA[buf] + ao + 2048);                    \
    const i32x8 b0 = *(const i32x8*)(lB[buf] + bo);                           \
    const i32x8 b1 = *(const i32x8*)(lB[buf] + bo + 2048);                    \
    __builtin_amdgcn_s_setprio(1);                                            \
    acc00 = __builtin_amdgcn_mfma_scale_f32_32x32x64_f8f6f4(                  \
        a0, b0, acc00, 0, 0, 0, 127, 0, 127);                                 \
    acc01 = __builtin_amdgcn_mfma_scale_f32_32x32x64_f8f6f4(                  \
        a0, b1, acc01, 0, 0, 0, 127, 0, 127);                                 \
    acc10 = __builtin_amdgcn_mfma_scale_f32_32x32x64_f8f6f4(                  \
        a1, b0, acc10, 0, 0, 0, 127, 0, 127);                                 \
    acc11 = __builtin_amdgcn_mfma_scale_f32_32x32x64_f8f6f4(                  \
        a1, b1, acc11, 0, 0, 0, 127, 0, 127);                                 \
    __builtin_amdgcn_s_setprio(0);                                            \
} while (0)

#define BAR() do { __builtin_amdgcn_s_barrier(); __builtin_amdgcn_sched_barrier(0); } while (0)
#define GATE3() asm volatile("s_waitcnt vmcnt(3)" ::: "memory")
#define GATE0() asm volatile("s_waitcnt vmcnt(0)" ::: "memory")

    const int NT = K >> 6;   // BK=64 steps (K=1024 -> 16)

    STAGE(0, 0);
    if ((NT & 1) == 0) {
        // static double-buffer: buf index compile-time per copy
        for (int t = 0; t < NT - 2; t += 2) {
            STAGE(1, t + 1); GATE3(); BAR(); COMPUTE(0); BAR();
            STAGE(0, t + 2); GATE3(); BAR(); COMPUTE(1); BAR();
        }
        STAGE(1, NT - 1); GATE3(); BAR(); COMPUTE(0); BAR();
        GATE0(); BAR(); COMPUTE(1);
    } else {
        for (int t = 0; t < NT - 1; ++t) {
            STAGE((t + 1) & 1, t + 1); GATE3(); BAR();
            if (t & 1) COMPUTE(1); else COMPUTE(0);
            BAR();
        }
        GATE0(); BAR();
        if ((NT - 1) & 1) COMPUTE(1); else COMPUTE(0);
    }

    // epilogue: 32x32 C/D layout (m74/m101): col = lane&31,
    // row = (reg&3) + 8*(reg>>2) + 4*(lane>>5).  (verified r9/r10)
    const float k1 = LOG2E / WSCALE;
    const int v0 = bn * 256 + wn * 64 + (lane & 31);
    const float fbv0 = fb[v0] * LOG2E,      bbv0 = bb[v0] * LOG2E;
    const float fbv1 = fb[v0 + 32] * LOG2E, bbv1 = bb[v0 + 32] * LOG2E;
    const int mb0 = bm * 128 + wm * 64 + ((lane >> 5) << 2);

#define EPI(T0, T1, MB) do {                                                  \
    _Pragma("unroll")                                                         \
    for (int reg = 0; reg < 16; ++reg) {                                      \
        const int m = (MB) + (reg & 3) + ((reg >> 2) << 3);                   \
        if (m < M) {   /* uniform across the 32-lane shuffle group */         \
            const bool isf = m < Nf;                                          \
            float ps = exp2f(fmaf(T0[reg], k1, isf ? fbv0 : bbv0))            \
                     + exp2f(fmaf(T1[reg], k1, isf ? fbv1 : bbv1));           \
            _Pragma("unroll")                                                 \
            for (int s = 1; s < 32; s <<= 1) ps += __shfl_xor(ps, s);         \
            if ((lane & 31) == 0) atomicAdd(&S[m], ps);                       \
        }                                                                     \
    }                                                                         \
} while (0)

    EPI(acc00, acc01, mb0);
    EPI(acc10, acc11, mb0 + 32);

#undef GLDS
#undef STAGE
#undef COMPUTE
#undef BAR
#undef GATE3
#undef GATE0
#undef EPI
}

// ---------------- fallback (ws too small): naive exact f32 sum-exp ----------
__global__ void lse_naive(const float* __restrict__ hs,
                          const float* __restrict__ W,
                          const float* __restrict__ fb,
                          const float* __restrict__ bb,
                          const int* __restrict__ row_ctx,
                          const int* __restrict__ hdr,
                          float* __restrict__ S, int D2, int D, int V) {
    const int m = blockIdx.x;
    const int M = hdr[0], Nf = hdr[1];
    if (m >= M) return;
    __shared__ float hrow[2048];
    const int ctx = row_ctx[m];
    const float* h = hs + (size_t)ctx * D2 + (m < Nf ? 0 : D);
    for (int i = threadIdx.x; i < D; i += blockDim.x) hrow[i] = h[i];
    __syncthreads();
    const float* bias = (m < Nf) ? fb : bb;
    float ps = 0.f;
    for (int v = threadIdx.x; v < V; v += blockDim.x) {
        const float* w = W + (size_t)v * D;
        float dot = 0.f;
        for (int k = 0; k < D; ++k) dot = fmaf(hrow[k], w[k], dot);
        ps += exp2f((dot + bias[v]) * LOG2E);
    }
#pragma unroll
    for (int d = 1; d < 64; d <<= 1) ps += __shfl_xor(ps, d);
    __shared__ float wsum[4];
    const int wid = threadIdx.x >> 6, lane = threadIdx.x & 63;
    if (lane == 0) wsum[wid] = ps;
    __syncthreads();
    if (threadIdx.x == 0) S[m] = wsum[0] + wsum[1] + wsum[2] + wsum[3];
}

// ---------------- gold logits (exact f32) ----------------
__global__ void gold_kernel(const float* __restrict__ hs,
                            const float* __restrict__ W,
                            const float* __restrict__ fb,
                            const float* __restrict__ bb,
                            const int* __restrict__ row_ctx,
                            const int* __restrict__ row_tok,
                            const int* __restrict__ hdr,
                            float* __restrict__ goldv, int D2, int D) {
    const int m = blockIdx.x;
    const int M = hdr[0];
    if (m >= M) return;
    const int Nf = hdr[1];
    const int ctx = row_ctx[m], tok = row_tok[m];
    const float4* h = (const float4*)(hs + (size_t)ctx * D2 + (m < Nf ? 0 : D));
    const float4* w = (const float4*)(W + (size_t)tok * D);
    float s = 0.f;
    for (int i = threadIdx.x; i < D / 4; i += blockDim.x) {
        float4 a = h[i], b = w[i];
        s += a.x * b.x + a.y * b.y + a.z * b.z + a.w * b.w;
    }
#pragma unroll
    for (int d = 1; d < 64; d <<= 1) s += __shfl_xor(s, d);
    __shared__ float wsum[4];
    const int wid = threadIdx.x >> 6, lane = threadIdx.x & 63;
    if (lane == 0) wsum[wid] = s;
    __syncthreads();
    if (threadIdx.x == 0) {
        float tot = wsum[0] + wsum[1] + wsum[2] + wsum[3];
        tot += (m < Nf ? fb[tok] : bb[tok]);
        goldv[m] = tot;
    }
}

// ---------------- final reduce ----------------
__global__ void final_kernel(const float* __restrict__ S,
                             const float* __restrict__ goldv,
                             const int* __restrict__ hdr,
                             const float* __restrict__ fhdr,
                             float* __restrict__ out) {
    const int M = hdr[0];
    float s = 0.f;
    for (int m = threadIdx.x; m < M; m += blockDim.x)
        s += logf(S[m]) - goldv[m];
#pragma unroll
    for (int d = 1; d < 64; d <<= 1) s += __shfl_xor(s, d);
    __shared__ float wsum[4];
    const int wid = threadIdx.x >> 6, lane = threadIdx.x & 63;
    if (lane == 0) wsum[wid] = s;
    __syncthreads();
    if (threadIdx.x == 0)
        out[0] = (wsum[0] + wsum[1] + wsum[2] + wsum[3]) / fhdr[0];
}

extern "C" void kernel_launch(void* const* d_in, const int* in_sizes, int n_in,
                              void* d_out, int out_size, void* d_ws, size_t ws_size,
                              hipStream_t stream) {
    const float* hs  = (const float*)d_in[0];
    const float* W   = (const float*)d_in[1];
    const float* fb  = (const float*)d_in[2];
    const float* bb  = (const float*)d_in[3];
    const int* sent  = (const int*)d_in[4];
    const int* bs    = (const int*)d_in[5];
    const int total  = in_sizes[4];
    const int T      = in_sizes[5];
    const int V      = in_sizes[2];
    const int D      = in_sizes[1] / V;
    const int D2     = in_sizes[0] / total;
    const int Mcap   = ((2 * total) + 127) & ~127;   // 128-aligned upper bound
    const int MT     = Mcap / 128;
    const int NN     = V / 256;

    char* p = (char*)d_ws;
    int*   hdr     = (int*)p;            p += 256;
    float* fhdr    = (float*)p;          p += 256;
    int*   row_ctx = (int*)p;            p += (size_t)Mcap * 4;
    int*   row_tok = (int*)p;            p += (size_t)Mcap * 4;
    float* S       = (float*)p;          p += (size_t)Mcap * 4;
    float* goldv   = (float*)p;          p += (size_t)Mcap * 4;
    uint8_t* Hc    = (uint8_t*)p;        p += (size_t)Mcap * D;     // fp8
    uint8_t* Wb    = (uint8_t*)p;
    const size_t need_wb = (size_t)(p - (char*)d_ws) + (size_t)V * D;

    prep_kernel<<<1, 256, 0, stream>>>(bs, T, sent, hdr, fhdr, row_ctx, row_tok);

    if (ws_size >= need_wb) {
        gather_kernel<<<MT * 4, 512, 0, stream>>>(hs, row_ctx, hdr, Hc, S, D2, D);
        wconv_kernel<<<(V / 256) * 8, 512, 0, stream>>>(W, Wb, D);
        gemm_lse<<<NN * MT, 512, 0, stream>>>(Hc, Wb, fb, bb, S, hdr, D, MT);
    } else {
        lse_naive<<<Mcap, 256, 0, stream>>>(hs, W, fb, bb, row_ctx, hdr, S, D2, D, V);
    }

    gold_kernel<<<Mcap, 256, 0, stream>>>(hs, W, fb, bb, row_ctx, row_tok, hdr, goldv, D2, D);
    final_kernel<<<1, 256, 0, stream>>>(S, goldv, hdr, fhdr, (float*)d_out);
}

// Round 12
// 295.817 us; speedup vs baseline: 1.0451x; 1.0451x over previous
//
#include <hip/hip_runtime.h>
#include <hip/hip_bf16.h>
#include <stdint.h>

typedef float f32x16 __attribute__((ext_vector_type(16)));
typedef int   i32x4  __attribute__((ext_vector_type(4)));
typedef int   i32x8  __attribute__((ext_vector_type(8)));

#define LOG2E 1.4426950408889634f
#define WSCALE 16.0f
#define AS1 __attribute__((address_space(1)))
#define AS3 __attribute__((address_space(3)))

// fp8 MX operand layout (r10-verified: absmax=0, SQ_LDS_BANK_CONFLICT=0):
// panel of R rows (R=128 A / 256 B) stored as
//   [k-tile t (64 k)][frag f (32 rows)][half h][lane l] x 16B
// chunk (f,h,l) holds row f*32+(l&31), k = t*64 + (l>>5)*32 + h*16 + 0..15.
// Fragment = {16B @ +0, 16B @ +1024} per lane; each half a contiguous 1KB
// wave read (conflict-free). Staging is a sequential byte-copy (base+tid*16).
// W pre-scaled x16; epilogue multiplies logits by 1/16. MX scale = E8M0 1.0
// (byte 127) == exact fp8 matmul.

// ---------------- f32 -> OCP e4m3 (RNE, clamp; verified r8-r11 absmax=0) ----
__device__ __forceinline__ uint32_t f32_to_e4m3(float x) {
    uint32_t ux = __float_as_uint(x);
    uint32_t s = (ux >> 24) & 0x80u;
    float a = __uint_as_float(ux & 0x7FFFFFFFu);
    if (a >= 448.0f) return s | 0x7Eu;
    int e = (int)((ux >> 23) & 0xFFu) - 127;
    if (e < -6) {
        int n = __float2int_rn(a * 512.0f);
        return s | (uint32_t)n;
    }
    uint32_t m = ux & 0x7FFFFFu;
    uint32_t r = (m + 0x7FFFFu + ((m >> 20) & 1u)) >> 20;
    if (r == 8u) { r = 0u; e += 1; }
    if (e > 8 || (e == 8 && r == 7u)) return s | 0x7Eu;
    return s | ((uint32_t)(e + 7) << 3) | r;
}

__device__ __forceinline__ uint32_t pack4_fp8v(float4 v, float sc) {
    return f32_to_e4m3(v.x * sc) | (f32_to_e4m3(v.y * sc) << 8) |
           (f32_to_e4m3(v.z * sc) << 16) | (f32_to_e4m3(v.w * sc) << 24);
}

__device__ __forceinline__ uint32_t pack4_fp8(const float* s, float sc) {
    return f32_to_e4m3(s[0] * sc) | (f32_to_e4m3(s[1] * sc) << 8) |
           (f32_to_e4m3(s[2] * sc) << 16) | (f32_to_e4m3(s[3] * sc) << 24);
}

__device__ __forceinline__ uint4 cvt16_fp8(const float* s, float sc) {
    uint4 r;
    r.x = pack4_fp8(s, sc);      r.y = pack4_fp8(s + 4, sc);
    r.z = pack4_fp8(s + 8, sc);  r.w = pack4_fp8(s + 12, sc);
    return r;
}

// ---------------- prep: build indices from batch_sizes ----------------
__global__ void prep_kernel(const int* __restrict__ bs, int T,
                            const int* __restrict__ sentences,
                            int* __restrict__ hdr, float* __restrict__ fhdr,
                            int* __restrict__ row_ctx, int* __restrict__ row_tok) {
    __shared__ int off[1025];
    if (threadIdx.x == 0) {
        int acc = 0; off[0] = 0;
        for (int t = 0; t < T; ++t) { acc += bs[t]; off[t + 1] = acc; }
    }
    __syncthreads();
    const int total = off[T];
    const int Nf = total - off[1];
    const int Nb = total - off[2];
    for (int t = 1; t < T; ++t) {
        int start = off[t] - off[1];
        int cnt = off[t + 1] - off[t];
        for (int p = threadIdx.x; p < cnt; p += blockDim.x) {
            row_ctx[start + p] = off[t - 1] + p;
            row_tok[start + p] = sentences[off[t] + p];
        }
    }
    for (int i = 1; i < T - 1; ++i) {
        int start = Nf + off[i + 1] - off[2];
        int cnt = off[i + 2] - off[i + 1];
        for (int p = threadIdx.x; p < cnt; p += blockDim.x) {
            row_ctx[start + p] = off[i + 1] + p;
            row_tok[start + p] = sentences[off[i] + p];
        }
    }
    if (threadIdx.x == 0) {
        hdr[0] = Nf + Nb;
        hdr[1] = Nf;
        int bs0 = off[1];
        int bsl = off[T] - off[T - 1];
        fhdr[0] = (float)(2 * total - bs0 - bsl);
    }
}

// ---------------- W f32 -> fp8 (x16), MX panels, LDS-staged transpose -------
// (verified r10: coalesced both sides, wconv off the top-5)
__global__ void wconv_kernel(const float* __restrict__ W,
                             uint8_t* __restrict__ Wb, int K) {
    const int p = blockIdx.x >> 3, f = blockIdx.x & 7;
    __shared__ __align__(16) char tile[2048];
    char* panel = (char*)Wb + (size_t)p * ((size_t)K << 8);   // 256 rows * K B
    const int tid = threadIdx.x;
    const int rloc = tid >> 4;            // 0..31
    const int kloc = (tid & 15) << 2;     // 0..60, step 4
    const int h = (kloc >> 4) & 1;
    const int l = ((kloc >> 5) << 5) | rloc;
    const int ldst = h * 1024 + l * 16 + (kloc & 15);
    const float* src = W + (size_t)(p * 256 + f * 32 + rloc) * K + kloc;
    const int NT = K >> 6;
    for (int t = 0; t < NT; ++t) {
        const float4 v = *(const float4*)(src + t * 64);
        const uint32_t pk = pack4_fp8v(v, WSCALE);
        __syncthreads();                              // prev write-out done
        *(uint32_t*)(tile + ldst) = pk;
        __syncthreads();
        if (tid < 128)
            *(uint4*)(panel + (size_t)t * 16384 + f * 2048 + (tid << 4)) =
                *(const uint4*)(tile + (tid << 4));
    }
}

// ---------------- gather ctx rows -> fp8 128-row MX panels, zero S ----------
// (verified r10)
__global__ void gather_kernel(const float* __restrict__ hs,
                              const int* __restrict__ row_ctx,
                              const int* __restrict__ hdr,
                              uint8_t* __restrict__ Hc,
                              float* __restrict__ S, int D2, int K) {
    const int p = blockIdx.x >> 2, f = blockIdx.x & 3;
    const int M = hdr[0], Nf = hdr[1];
    if (f == 0 && threadIdx.x < 128) S[p * 128 + threadIdx.x] = 0.f;
    char* panel = (char*)Hc + (size_t)p * ((size_t)K << 7);   // 128 rows * K B
    const int row0 = p * 128 + f * 32;
    const int nch = (K >> 6) << 7;
    for (int c = threadIdx.x; c < nch; c += 512) {
        const int t = c >> 7, h = (c >> 6) & 1, l = c & 63;
        const int row = row0 + (l & 31);
        char* d = panel + (size_t)t * 8192 + f * 2048 + h * 1024 + l * 16;
        if (row >= M) {
            uint4 z; z.x = z.y = z.z = z.w = 0u;
            *(uint4*)d = z;
        } else {
            const int ctx = row_ctx[row];
            const int k = t * 64 + ((l >> 5) << 5) + h * 16;
            *(uint4*)d = cvt16_fp8(hs + (size_t)ctx * D2 + (row < Nf ? 0 : K) + k, 1.0f);
        }
    }
}

// ---------------- main 128x256 / BK=64 / 8-wave MX-fp8 GEMM + sum-exp -------
// r10's verified kernel + 3-deep buffer pipeline: step t stages tile t+2,
// gates vmcnt(6) (9 outstanding, 6 newer than t -> t landed for all waves).
// Buffer safety: STAGE into buf (t+2)%3 == (t-1)%3, whose reads completed
// before the end-of-step-(t-1) barrier. Lookahead = 2 full steps.
__device__ __forceinline__ i32x8 ld_frag(const char* base) {
    i32x4 lo = *(const i32x4*)(base);
    i32x4 hi = *(const i32x4*)(base + 1024);
    i32x8 r;
    r[0] = lo[0]; r[1] = lo[1]; r[2] = lo[2]; r[3] = lo[3];
    r[4] = hi[0]; r[5] = hi[1]; r[6] = hi[2]; r[7] = hi[3];
    return r;
}

__global__ __launch_bounds__(512, 4)
void gemm_lse(const uint8_t* __restrict__ A,
              const uint8_t* __restrict__ B,
              const float* __restrict__ fb,
              const float* __restrict__ bb,
              float* __restrict__ S,
              const int* __restrict__ hdr, int K, int MT) {
    const int M = hdr[0], Nf = hdr[1];

    // XCD-aware bijective swizzle (m204), bm-fastest (verified r2/r6/r8).
    const int nwg = gridDim.x, orig = blockIdx.x;
    const int q = nwg >> 3, rr = nwg & 7;
    const int xcd = orig & 7, i8 = orig >> 3;
    const int wgid = (xcd < rr ? xcd * (q + 1) : rr * (q + 1) + (xcd - rr) * q) + i8;
    const int bm = wgid % MT, bn = wgid / MT;
    if (bm * 128 >= M) return;

    __shared__ __align__(16) char lA[3][8192];     // BK=64 of A (128 rows)
    __shared__ __align__(16) char lB[3][16384];    // BK=64 of B (256 rows)

    const int tid = threadIdx.x, lane = tid & 63, wid = tid >> 6;
    const int wm = wid >> 2, wn = wid & 3;     // 2M x 4N waves, each 64x64 out

    f32x16 acc00 = (f32x16)0.f, acc01 = (f32x16)0.f;
    f32x16 acc10 = (f32x16)0.f, acc11 = (f32x16)0.f;

    const char* Ap = (const char*)A + (size_t)bm * ((size_t)K << 7);
    const char* Bp = (const char*)B + (size_t)bn * ((size_t)K << 8);
    const int sd = tid << 4;
    const int ao = ((wm * 2) << 11) + (lane << 4);   // + mf*2048
    const int bo = ((wn * 2) << 11) + (lane << 4);   // + nf*2048

#define GLDS(src, dst) __builtin_amdgcn_global_load_lds(                      \
        (const AS1 uint32_t*)(src), (AS3 uint32_t*)(dst), 16, 0, 0)

#define STAGE(buf, s) do {                                                    \
    GLDS(Ap + ((size_t)(s) << 13) + sd,        lA[buf] + sd);                 \
    GLDS(Bp + ((size_t)(s) << 14) + sd,        lB[buf] + sd);                 \
    GLDS(Bp + ((size_t)(s) << 14) + 8192 + sd, lB[buf] + 8192 + sd);          \
} while (0)

#define COMPUTE(buf) do {                                                     \
    const i32x8 a0 = ld_frag(lA[buf] + ao);                                   \
    const i32x8 a1 = ld_frag(lA[buf] + ao + 2048);                            \
    const i32x8 b0 = ld_frag(lB[buf] + bo);                                   \
    const i32x8 b1 = ld_frag(lB[buf] + bo + 2048);                            \
    __builtin_amdgcn_s_setprio(1);                                            \
    acc00 = __builtin_amdgcn_mfma_scale_f32_32x32x64_f8f6f4(                  \
        a0, b0, acc00, 0, 0, 0, 127, 0, 127);                                 \
    acc01 = __builtin_amdgcn_mfma_scale_f32_32x32x64_f8f6f4(                  \
        a0, b1, acc01, 0, 0, 0, 127, 0, 127);                                 \
    acc10 = __builtin_amdgcn_mfma_scale_f32_32x32x64_f8f6f4(                  \
        a1, b0, acc10, 0, 0, 0, 127, 0, 127);                                 \
    acc11 = __builtin_amdgcn_mfma_scale_f32_32x32x64_f8f6f4(                  \
        a1, b1, acc11, 0, 0, 0, 127, 0, 127);                                 \
    __builtin_amdgcn_s_setprio(0);                                            \
} while (0)

#define BAR() do { __builtin_amdgcn_s_barrier(); __builtin_amdgcn_sched_barrier(0); } while (0)
#define GATE6() asm volatile("s_waitcnt vmcnt(6)" ::: "memory")
#define GATE3() asm volatile("s_waitcnt vmcnt(3)" ::: "memory")
#define GATE0() asm volatile("s_waitcnt vmcnt(0)" ::: "memory")

    const int NT = K >> 6;   // BK=64 steps (K=1024 -> 16)

    if (NT == 16) {
        // 3-deep pipeline, fully unrolled so %3 buffer indices fold to consts
        STAGE(0, 0); STAGE(1, 1);
#pragma unroll
        for (int t = 0; t < 14; ++t) {
            STAGE((t + 2) % 3, t + 2);   // issue 2 steps ahead
            GATE6(); BAR();
            COMPUTE(t % 3);
            BAR();
        }
        GATE3(); BAR(); COMPUTE(2); BAR();   // t=14 (tile 15's 3 loads fly)
        GATE0(); BAR(); COMPUTE(0);          // t=15
    } else {
        // generic 2-buffer fallback (r10 schedule)
        STAGE(0, 0);
        for (int t = 0; t < NT - 1; ++t) {
            STAGE((t + 1) % 3, t + 1);
            GATE3(); BAR();
            COMPUTE(t % 3);
            BAR();
        }
        GATE0(); BAR();
        COMPUTE((NT - 1) % 3);
    }

    // epilogue: 32x32 C/D layout (m74/m101): col = lane&31,
    // row = (reg&3) + 8*(reg>>2) + 4*(lane>>5).  (verified r9-r11)
    const float k1 = LOG2E / WSCALE;
    const int v0 = bn * 256 + wn * 64 + (lane & 31);
    const float fbv0 = fb[v0] * LOG2E,      bbv0 = bb[v0] * LOG2E;
    const float fbv1 = fb[v0 + 32] * LOG2E, bbv1 = bb[v0 + 32] * LOG2E;
    const int mb0 = bm * 128 + wm * 64 + ((lane >> 5) << 2);

#define EPI(T0, T1, MB) do {                                                  \
    _Pragma("unroll")                                                         \
    for (int reg = 0; reg < 16; ++reg) {                                      \
        const int m = (MB) + (reg & 3) + ((reg >> 2) << 3);                   \
        if (m < M) {   /* uniform across the 32-lane shuffle group */         \
            const bool isf = m < Nf;                                          \
            float ps = exp2f(fmaf(T0[reg], k1, isf ? fbv0 : bbv0))            \
                     + exp2f(fmaf(T1[reg], k1, isf ? fbv1 : bbv1));           \
            _Pragma("unroll")                                                 \
            for (int s = 1; s < 32; s <<= 1) ps += __shfl_xor(ps, s);         \
            if ((lane & 31) == 0) atomicAdd(&S[m], ps);                       \
        }                                                                     \
    }                                                                         \
} while (0)

    EPI(acc00, acc01, mb0);
    EPI(acc10, acc11, mb0 + 32);

#undef GLDS
#undef STAGE
#undef COMPUTE
#undef BAR
#undef GATE6
#undef GATE3
#undef GATE0
#undef EPI
}

// ---------------- fallback (ws too small): naive exact f32 sum-exp ----------
__global__ void lse_naive(const float* __restrict__ hs,
                          const float* __restrict__ W,
                          const float* __restrict__ fb,
                          const float* __restrict__ bb,
                          const int* __restrict__ row_ctx,
                          const int* __restrict__ hdr,
                          float* __restrict__ S, int D2, int D, int V) {
    const int m = blockIdx.x;
    const int M = hdr[0], Nf = hdr[1];
    if (m >= M) return;
    __shared__ float hrow[2048];
    const int ctx = row_ctx[m];
    const float* h = hs + (size_t)ctx * D2 + (m < Nf ? 0 : D);
    for (int i = threadIdx.x; i < D; i += blockDim.x) hrow[i] = h[i];
    __syncthreads();
    const float* bias = (m < Nf) ? fb : bb;
    float ps = 0.f;
    for (int v = threadIdx.x; v < V; v += blockDim.x) {
        const float* w = W + (size_t)v * D;
        float dot = 0.f;
        for (int k = 0; k < D; ++k) dot = fmaf(hrow[k], w[k], dot);
        ps += exp2f((dot + bias[v]) * LOG2E);
    }
#pragma unroll
    for (int d = 1; d < 64; d <<= 1) ps += __shfl_xor(ps, d);
    __shared__ float wsum[4];
    const int wid = threadIdx.x >> 6, lane = threadIdx.x & 63;
    if (lane == 0) wsum[wid] = ps;
    __syncthreads();
    if (threadIdx.x == 0) S[m] = wsum[0] + wsum[1] + wsum[2] + wsum[3];
}

// ---------------- gold logits (exact f32) ----------------
__global__ void gold_kernel(const float* __restrict__ hs,
                            const float* __restrict__ W,
                            const float* __restrict__ fb,
                            const float* __restrict__ bb,
                            const int* __restrict__ row_ctx,
                            const int* __restrict__ row_tok,
                            const int* __restrict__ hdr,
                            float* __restrict__ goldv, int D2, int D) {
    const int m = blockIdx.x;
    const int M = hdr[0];
    if (m >= M) return;
    const int Nf = hdr[1];
    const int ctx = row_ctx[m], tok = row_tok[m];
    const float4* h = (const float4*)(hs + (size_t)ctx * D2 + (m < Nf ? 0 : D));
    const float4* w = (const float4*)(W + (size_t)tok * D);
    float s = 0.f;
    for (int i = threadIdx.x; i < D / 4; i += blockDim.x) {
        float4 a = h[i], b = w[i];
        s += a.x * b.x + a.y * b.y + a.z * b.z + a.w * b.w;
    }
#pragma unroll
    for (int d = 1; d < 64; d <<= 1) s += __shfl_xor(s, d);
    __shared__ float wsum[4];
    const int wid = threadIdx.x >> 6, lane = threadIdx.x & 63;
    if (lane == 0) wsum[wid] = s;
    __syncthreads();
    if (threadIdx.x == 0) {
        float tot = wsum[0] + wsum[1] + wsum[2] + wsum[3];
        tot += (m < Nf ? fb[tok] : bb[tok]);
        goldv[m] = tot;
    }
}

// ---------------- final reduce ----------------
__global__ void final_kernel(const float* __restrict__ S,
                             const float* __restrict__ goldv,
                             const int* __restrict__ hdr,
                             const float* __restrict__ fhdr,
                             float* __restrict__ out) {
    const int M = hdr[0];
    float s = 0.f;
    for (int m = threadIdx.x; m < M; m += blockDim.x)
        s += logf(S[m]) - goldv[m];
#pragma unroll
    for (int d = 1; d < 64; d <<= 1) s += __shfl_xor(s, d);
    __shared__ float wsum[4];
    const int wid = threadIdx.x >> 6, lane = threadIdx.x & 63;
    if (lane == 0) wsum[wid] = s;
    __syncthreads();
    if (threadIdx.x == 0)
        out[0] = (wsum[0] + wsum[1] + wsum[2] + wsum[3]) / fhdr[0];
}

extern "C" void kernel_launch(void* const* d_in, const int* in_sizes, int n_in,
                              void* d_out, int out_size, void* d_ws, size_t ws_size,
                              hipStream_t stream) {
    const float* hs  = (const float*)d_in[0];
    const float* W   = (const float*)d_in[1];
    const float* fb  = (const float*)d_in[2];
    const float* bb  = (const float*)d_in[3];
    const int* sent  = (const int*)d_in[4];
    const int* bs    = (const int*)d_in[5];
    const int total  = in_sizes[4];
    const int T      = in_sizes[5];
    const int V      = in_sizes[2];
    const int D      = in_sizes[1] / V;
    const int D2     = in_sizes[0] / total;
    const int Mcap   = ((2 * total) + 127) & ~127;   // 128-aligned upper bound
    const int MT     = Mcap / 128;
    const int NN     = V / 256;

    char* p = (char*)d_ws;
    int*   hdr     = (int*)p;            p += 256;
    float* fhdr    = (float*)p;          p += 256;
    int*   row_ctx = (int*)p;            p += (size_t)Mcap * 4;
    int*   row_tok = (int*)p;            p += (size_t)Mcap * 4;
    float* S       = (float*)p;          p += (size_t)Mcap * 4;
    float* goldv   = (float*)p;          p += (size_t)Mcap * 4;
    uint8_t* Hc    = (uint8_t*)p;        p += (size_t)Mcap * D;     // fp8
    uint8_t* Wb    = (uint8_t*)p;
    const size_t need_wb = (size_t)(p - (char*)d_ws) + (size_t)V * D;

    prep_kernel<<<1, 256, 0, stream>>>(bs, T, sent, hdr, fhdr, row_ctx, row_tok);

    if (ws_size >= need_wb) {
        gather_kernel<<<MT * 4, 512, 0, stream>>>(hs, row_ctx, hdr, Hc, S, D2, D);
        wconv_kernel<<<(V / 256) * 8, 512, 0, stream>>>(W, Wb, D);
        gemm_lse<<<NN * MT, 512, 0, stream>>>(Hc, Wb, fb, bb, S, hdr, D, MT);
    } else {
        lse_naive<<<Mcap, 256, 0, stream>>>(hs, W, fb, bb, row_ctx, hdr, S, D2, D, V);
    }

    gold_kernel<<<Mcap, 256, 0, stream>>>(hs, W, fb, bb, row_ctx, row_tok, hdr, goldv, D2, D);
    final_kernel<<<1, 256, 0, stream>>>(S, goldv, hdr, fhdr, (float*)d_out);
}

// Round 13
// 283.461 us; speedup vs baseline: 1.0907x; 1.0436x over previous
//
#include <hip/hip_runtime.h>
#include <hip/hip_bf16.h>
#include <stdint.h>

typedef float f32x16 __attribute__((ext_vector_type(16)));
typedef int   i32x4  __attribute__((ext_vector_type(4)));
typedef int   i32x8  __attribute__((ext_vector_type(8)));

#define LOG2E 1.4426950408889634f
#define WSCALE 16.0f

// fp8 MX operand layout (r10/r12-verified: absmax=0, conflicts=0):
// panel of R rows (R=128 A / 256 B) stored as
//   [k-tile t (64 k)][frag f (32 rows)][half h][lane l] x 16B
// chunk (f,h,l) holds row f*32+(l&31), k = t*64 + (l>>5)*32 + h*16 + 0..15.
// NEW (r13): panels are consumed DIRECTLY from global memory into registers —
// a wave's fragment is 2 coalesced global_load_dwordx4 (lo/hi 1KB segments).
// No LDS, no barriers, no waitcnt asm: reuse via L1/L2 (B panel L2-resident
// across the 28 bm-blocks per XCD; A fully L2/LLC-resident), latency hidden
// by 2-deep register pipeline + 3 waves/SIMD TLP.
// W pre-scaled x16; epilogue multiplies logits by 1/16. MX scale = E8M0 1.0
// (byte 127) == exact fp8 matmul.

// ---------------- f32 -> OCP e4m3 (RNE, clamp; verified r8-r12 absmax=0) ----
__device__ __forceinline__ uint32_t f32_to_e4m3(float x) {
    uint32_t ux = __float_as_uint(x);
    uint32_t s = (ux >> 24) & 0x80u;
    float a = __uint_as_float(ux & 0x7FFFFFFFu);
    if (a >= 448.0f) return s | 0x7Eu;
    int e = (int)((ux >> 23) & 0xFFu) - 127;
    if (e < -6) {
        int n = __float2int_rn(a * 512.0f);
        return s | (uint32_t)n;
    }
    uint32_t m = ux & 0x7FFFFFu;
    uint32_t r = (m + 0x7FFFFu + ((m >> 20) & 1u)) >> 20;
    if (r == 8u) { r = 0u; e += 1; }
    if (e > 8 || (e == 8 && r == 7u)) return s | 0x7Eu;
    return s | ((uint32_t)(e + 7) << 3) | r;
}

__device__ __forceinline__ uint32_t pack4_fp8v(float4 v, float sc) {
    return f32_to_e4m3(v.x * sc) | (f32_to_e4m3(v.y * sc) << 8) |
           (f32_to_e4m3(v.z * sc) << 16) | (f32_to_e4m3(v.w * sc) << 24);
}

__device__ __forceinline__ uint32_t pack4_fp8(const float* s, float sc) {
    return f32_to_e4m3(s[0] * sc) | (f32_to_e4m3(s[1] * sc) << 8) |
           (f32_to_e4m3(s[2] * sc) << 16) | (f32_to_e4m3(s[3] * sc) << 24);
}

__device__ __forceinline__ uint4 cvt16_fp8(const float* s, float sc) {
    uint4 r;
    r.x = pack4_fp8(s, sc);      r.y = pack4_fp8(s + 4, sc);
    r.z = pack4_fp8(s + 8, sc);  r.w = pack4_fp8(s + 12, sc);
    return r;
}

// ---------------- prep: build indices from batch_sizes ----------------
__global__ void prep_kernel(const int* __restrict__ bs, int T,
                            const int* __restrict__ sentences,
                            int* __restrict__ hdr, float* __restrict__ fhdr,
                            int* __restrict__ row_ctx, int* __restrict__ row_tok) {
    __shared__ int off[1025];
    if (threadIdx.x == 0) {
        int acc = 0; off[0] = 0;
        for (int t = 0; t < T; ++t) { acc += bs[t]; off[t + 1] = acc; }
    }
    __syncthreads();
    const int total = off[T];
    const int Nf = total - off[1];
    const int Nb = total - off[2];
    for (int t = 1; t < T; ++t) {
        int start = off[t] - off[1];
        int cnt = off[t + 1] - off[t];
        for (int p = threadIdx.x; p < cnt; p += blockDim.x) {
            row_ctx[start + p] = off[t - 1] + p;
            row_tok[start + p] = sentences[off[t] + p];
        }
    }
    for (int i = 1; i < T - 1; ++i) {
        int start = Nf + off[i + 1] - off[2];
        int cnt = off[i + 2] - off[i + 1];
        for (int p = threadIdx.x; p < cnt; p += blockDim.x) {
            row_ctx[start + p] = off[i + 1] + p;
            row_tok[start + p] = sentences[off[i] + p];
        }
    }
    if (threadIdx.x == 0) {
        hdr[0] = Nf + Nb;
        hdr[1] = Nf;
        int bs0 = off[1];
        int bsl = off[T] - off[T - 1];
        fhdr[0] = (float)(2 * total - bs0 - bsl);
    }
}

// ---------------- W f32 -> fp8 (x16), MX panels, LDS-staged transpose -------
// (verified r10/r12: coalesced both sides)
__global__ void wconv_kernel(const float* __restrict__ W,
                             uint8_t* __restrict__ Wb, int K) {
    const int p = blockIdx.x >> 3, f = blockIdx.x & 7;
    __shared__ __align__(16) char tile[2048];
    char* panel = (char*)Wb + (size_t)p * ((size_t)K << 8);   // 256 rows * K B
    const int tid = threadIdx.x;
    const int rloc = tid >> 4;            // 0..31
    const int kloc = (tid & 15) << 2;     // 0..60, step 4
    const int h = (kloc >> 4) & 1;
    const int l = ((kloc >> 5) << 5) | rloc;
    const int ldst = h * 1024 + l * 16 + (kloc & 15);
    const float* src = W + (size_t)(p * 256 + f * 32 + rloc) * K + kloc;
    const int NT = K >> 6;
    for (int t = 0; t < NT; ++t) {
        const float4 v = *(const float4*)(src + t * 64);
        const uint32_t pk = pack4_fp8v(v, WSCALE);
        __syncthreads();                              // prev write-out done
        *(uint32_t*)(tile + ldst) = pk;
        __syncthreads();
        if (tid < 128)
            *(uint4*)(panel + (size_t)t * 16384 + f * 2048 + (tid << 4)) =
                *(const uint4*)(tile + (tid << 4));
    }
}

// ---------------- gather ctx rows -> fp8 128-row MX panels, zero S ----------
// (verified r10/r12)
__global__ void gather_kernel(const float* __restrict__ hs,
                              const int* __restrict__ row_ctx,
                              const int* __restrict__ hdr,
                              uint8_t* __restrict__ Hc,
                              float* __restrict__ S, int D2, int K) {
    const int p = blockIdx.x >> 2, f = blockIdx.x & 3;
    const int M = hdr[0], Nf = hdr[1];
    if (f == 0 && threadIdx.x < 128) S[p * 128 + threadIdx.x] = 0.f;
    char* panel = (char*)Hc + (size_t)p * ((size_t)K << 7);   // 128 rows * K B
    const int row0 = p * 128 + f * 32;
    const int nch = (K >> 6) << 7;
    for (int c = threadIdx.x; c < nch; c += 512) {
        const int t = c >> 7, h = (c >> 6) & 1, l = c & 63;
        const int row = row0 + (l & 31);
        char* d = panel + (size_t)t * 8192 + f * 2048 + h * 1024 + l * 16;
        if (row >= M) {
            uint4 z; z.x = z.y = z.z = z.w = 0u;
            *(uint4*)d = z;
        } else {
            const int ctx = row_ctx[row];
            const int k = t * 64 + ((l >> 5) << 5) + h * 16;
            *(uint4*)d = cvt16_fp8(hs + (size_t)ctx * D2 + (row < Nf ? 0 : K) + k, 1.0f);
        }
    }
}

// ---------------- main 128x128 / 4-wave direct-from-L2 MX-fp8 GEMM ----------
// No LDS, no barriers: each wave streams its 4 fragments per K-step from the
// fragment-ordered panels (2 coalesced dwordx4 per fragment) into registers,
// 2-deep register pipeline (compiler inserts counted vmcnt), 4 MFMA/step.
__global__ __launch_bounds__(256, 3)
void gemm_lse(const uint8_t* __restrict__ A,
              const uint8_t* __restrict__ B,
              const float* __restrict__ fb,
              const float* __restrict__ bb,
              float* __restrict__ S,
              const int* __restrict__ hdr, int K, int MT) {
    const int M = hdr[0], Nf = hdr[1];

    // XCD-aware bijective swizzle (m204), bm-fastest: the 28 blocks sharing a
    // B half-panel run consecutively on one XCD -> B L2-resident.
    const int nwg = gridDim.x, orig = blockIdx.x;
    const int q = nwg >> 3, rr = nwg & 7;
    const int xcd = orig & 7, i8 = orig >> 3;
    const int wgid = (xcd < rr ? xcd * (q + 1) : rr * (q + 1) + (xcd - rr) * q) + i8;
    const int bm = wgid % MT, bn = wgid / MT;
    if (bm * 128 >= M) return;

    const int tid = threadIdx.x, lane = tid & 63, wid = tid >> 6;
    const int wm = wid >> 1, wn = wid & 1;       // 2x2 waves, each 64x64 out

    f32x16 acc00 = (f32x16)0.f, acc01 = (f32x16)0.f;
    f32x16 acc10 = (f32x16)0.f, acc11 = (f32x16)0.f;

    // per-wave fragment base pointers (fragment order == memory order)
    const char* pa = (const char*)A + (size_t)bm * ((size_t)K << 7)
                     + (wm << 12) + (lane << 4);            // step stride 8192
    const char* pb = (const char*)B + (size_t)(bn >> 1) * ((size_t)K << 8)
                     + ((bn & 1) << 13) + (wn << 12) + (lane << 4); // stride 16384

    i32x4 xa0l, xa0h, xa1l, xa1h, xb0l, xb0h, xb1l, xb1h;   // pipeline set X
    i32x4 ya0l, ya0h, ya1l, ya1h, yb0l, yb0h, yb1l, yb1h;   // pipeline set Y

#define LOADS(P, t) do {                                                      \
    const char* _a = pa + (size_t)(t) * 8192;                                 \
    const char* _b = pb + (size_t)(t) * 16384;                                \
    P##a0l = *(const i32x4*)(_a);          P##a0h = *(const i32x4*)(_a + 1024); \
    P##a1l = *(const i32x4*)(_a + 2048);   P##a1h = *(const i32x4*)(_a + 3072); \
    P##b0l = *(const i32x4*)(_b);          P##b0h = *(const i32x4*)(_b + 1024); \
    P##b1l = *(const i32x4*)(_b + 2048);   P##b1h = *(const i32x4*)(_b + 3072); \
} while (0)

#define CAT8(lo, hi) __builtin_shufflevector(lo, hi, 0, 1, 2, 3, 4, 5, 6, 7)

#define COMP(P) do {                                                          \
    const i32x8 A0 = CAT8(P##a0l, P##a0h);                                    \
    const i32x8 A1 = CAT8(P##a1l, P##a1h);                                    \
    const i32x8 B0 = CAT8(P##b0l, P##b0h);                                    \
    const i32x8 B1 = CAT8(P##b1l, P##b1h);                                    \
    acc00 = __builtin_amdgcn_mfma_scale_f32_32x32x64_f8f6f4(                  \
        A0, B0, acc00, 0, 0, 0, 127, 0, 127);                                 \
    acc01 = __builtin_amdgcn_mfma_scale_f32_32x32x64_f8f6f4(                  \
        A0, B1, acc01, 0, 0, 0, 127, 0, 127);                                 \
    acc10 = __builtin_amdgcn_mfma_scale_f32_32x32x64_f8f6f4(                  \
        A1, B0, acc10, 0, 0, 0, 127, 0, 127);                                 \
    acc11 = __builtin_amdgcn_mfma_scale_f32_32x32x64_f8f6f4(                  \
        A1, B1, acc11, 0, 0, 0, 127, 0, 127);                                 \
} while (0)

    const int NT = K >> 6;   // 64-k steps (K=1024 -> 16)

    LOADS(x, 0);
    int t = 0;
    for (; t + 2 < NT; t += 2) {
        LOADS(y, t + 1);     // in flight while COMP(x)'s MFMAs run
        COMP(x);
        LOADS(x, t + 2);
        COMP(y);
    }
    if ((NT & 1) == 0) {     // t == NT-2
        LOADS(y, t + 1);
        COMP(x);
        COMP(y);
    } else {                 // t == NT-1
        COMP(x);
    }

    // epilogue: 32x32 C/D layout (m74/m101): col = lane&31,
    // row = (reg&3) + 8*(reg>>2) + 4*(lane>>5).  (verified r9-r12)
    const float k1 = LOG2E / WSCALE;
    const int v0 = bn * 128 + wn * 64 + (lane & 31);
    const float fbv0 = fb[v0] * LOG2E,      bbv0 = bb[v0] * LOG2E;
    const float fbv1 = fb[v0 + 32] * LOG2E, bbv1 = bb[v0 + 32] * LOG2E;
    const int mb0 = bm * 128 + wm * 64 + ((lane >> 5) << 2);

#define EPI(T0, T1, MB) do {                                                  \
    _Pragma("unroll")                                                         \
    for (int reg = 0; reg < 16; ++reg) {                                      \
        const int m = (MB) + (reg & 3) + ((reg >> 2) << 3);                   \
        if (m < M) {   /* uniform across each 32-lane shuffle group */        \
            const bool isf = m < Nf;                                          \
            float ps = exp2f(fmaf(T0[reg], k1, isf ? fbv0 : bbv0))            \
                     + exp2f(fmaf(T1[reg], k1, isf ? fbv1 : bbv1));           \
            _Pragma("unroll")                                                 \
            for (int s = 1; s < 32; s <<= 1) ps += __shfl_xor(ps, s);         \
            if ((lane & 31) == 0) atomicAdd(&S[m], ps);                       \
        }                                                                     \
    }                                                                         \
} while (0)

    EPI(acc00, acc01, mb0);
    EPI(acc10, acc11, mb0 + 32);

#undef LOADS
#undef CAT8
#undef COMP
#undef EPI
}

// ---------------- fallback (ws too small): naive exact f32 sum-exp ----------
__global__ void lse_naive(const float* __restrict__ hs,
                          const float* __restrict__ W,
                          const float* __restrict__ fb,
                          const float* __restrict__ bb,
                          const int* __restrict__ row_ctx,
                          const int* __restrict__ hdr,
                          float* __restrict__ S, int D2, int D, int V) {
    const int m = blockIdx.x;
    const int M = hdr[0], Nf = hdr[1];
    if (m >= M) return;
    __shared__ float hrow[2048];
    const int ctx = row_ctx[m];
    const float* h = hs + (size_t)ctx * D2 + (m < Nf ? 0 : D);
    for (int i = threadIdx.x; i < D; i += blockDim.x) hrow[i] = h[i];
    __syncthreads();
    const float* bias = (m < Nf) ? fb : bb;
    float ps = 0.f;
    for (int v = threadIdx.x; v < V; v += blockDim.x) {
        const float* w = W + (size_t)v * D;
        float dot = 0.f;
        for (int k = 0; k < D; ++k) dot = fmaf(hrow[k], w[k], dot);
        ps += exp2f((dot + bias[v]) * LOG2E);
    }
#pragma unroll
    for (int d = 1; d < 64; d <<= 1) ps += __shfl_xor(ps, d);
    __shared__ float wsum[4];
    const int wid = threadIdx.x >> 6, lane = threadIdx.x & 63;
    if (lane == 0) wsum[wid] = ps;
    __syncthreads();
    if (threadIdx.x == 0) S[m] = wsum[0] + wsum[1] + wsum[2] + wsum[3];
}

// ---------------- gold logits (exact f32) ----------------
__global__ void gold_kernel(const float* __restrict__ hs,
                            const float* __restrict__ W,
                            const float* __restrict__ fb,
                            const float* __restrict__ bb,
                            const int* __restrict__ row_ctx,
                            const int* __restrict__ row_tok,
                            const int* __restrict__ hdr,
                            float* __restrict__ goldv, int D2, int D) {
    const int m = blockIdx.x;
    const int M = hdr[0];
    if (m >= M) return;
    const int Nf = hdr[1];
    const int ctx = row_ctx[m], tok = row_tok[m];
    const float4* h = (const float4*)(hs + (size_t)ctx * D2 + (m < Nf ? 0 : D));
    const float4* w = (const float4*)(W + (size_t)tok * D);
    float s = 0.f;
    for (int i = threadIdx.x; i < D / 4; i += blockDim.x) {
        float4 a = h[i], b = w[i];
        s += a.x * b.x + a.y * b.y + a.z * b.z + a.w * b.w;
    }
#pragma unroll
    for (int d = 1; d < 64; d <<= 1) s += __shfl_xor(s, d);
    __shared__ float wsum[4];
    const int wid = threadIdx.x >> 6, lane = threadIdx.x & 63;
    if (lane == 0) wsum[wid] = s;
    __syncthreads();
    if (threadIdx.x == 0) {
        float tot = wsum[0] + wsum[1] + wsum[2] + wsum[3];
        tot += (m < Nf ? fb[tok] : bb[tok]);
        goldv[m] = tot;
    }
}

// ---------------- final reduce ----------------
__global__ void final_kernel(const float* __restrict__ S,
                             const float* __restrict__ goldv,
                             const int* __restrict__ hdr,
                             const float* __restrict__ fhdr,
                             float* __restrict__ out) {
    const int M = hdr[0];
    float s = 0.f;
    for (int m = threadIdx.x; m < M; m += blockDim.x)
        s += logf(S[m]) - goldv[m];
#pragma unroll
    for (int d = 1; d < 64; d <<= 1) s += __shfl_xor(s, d);
    __shared__ float wsum[4];
    const int wid = threadIdx.x >> 6, lane = threadIdx.x & 63;
    if (lane == 0) wsum[wid] = s;
    __syncthreads();
    if (threadIdx.x == 0)
        out[0] = (wsum[0] + wsum[1] + wsum[2] + wsum[3]) / fhdr[0];
}

extern "C" void kernel_launch(void* const* d_in, const int* in_sizes, int n_in,
                              void* d_out, int out_size, void* d_ws, size_t ws_size,
                              hipStream_t stream) {
    const float* hs  = (const float*)d_in[0];
    const float* W   = (const float*)d_in[1];
    const float* fb  = (const float*)d_in[2];
    const float* bb  = (const float*)d_in[3];
    const int* sent  = (const int*)d_in[4];
    const int* bs    = (const int*)d_in[5];
    const int total  = in_sizes[4];
    const int T      = in_sizes[5];
    const int V      = in_sizes[2];
    const int D      = in_sizes[1] / V;
    const int D2     = in_sizes[0] / total;
    const int Mcap   = ((2 * total) + 127) & ~127;   // 128-aligned upper bound
    const int MT     = Mcap / 128;
    const int NN2    = V / 128;

    char* p = (char*)d_ws;
    int*   hdr     = (int*)p;            p += 256;
    float* fhdr    = (float*)p;          p += 256;
    int*   row_ctx = (int*)p;            p += (size_t)Mcap * 4;
    int*   row_tok = (int*)p;            p += (size_t)Mcap * 4;
    float* S       = (float*)p;          p += (size_t)Mcap * 4;
    float* goldv   = (float*)p;          p += (size_t)Mcap * 4;
    uint8_t* Hc    = (uint8_t*)p;        p += (size_t)Mcap * D;     // fp8
    uint8_t* Wb    = (uint8_t*)p;
    const size_t need_wb = (size_t)(p - (char*)d_ws) + (size_t)V * D;

    prep_kernel<<<1, 256, 0, stream>>>(bs, T, sent, hdr, fhdr, row_ctx, row_tok);

    if (ws_size >= need_wb) {
        gather_kernel<<<MT * 4, 512, 0, stream>>>(hs, row_ctx, hdr, Hc, S, D2, D);
        wconv_kernel<<<(V / 256) * 8, 512, 0, stream>>>(W, Wb, D);
        gemm_lse<<<NN2 * MT, 256, 0, stream>>>(Hc, Wb, fb, bb, S, hdr, D, MT);
    } else {
        lse_naive<<<Mcap, 256, 0, stream>>>(hs, W, fb, bb, row_ctx, hdr, S, D2, D, V);
    }

    gold_kernel<<<Mcap, 256, 0, stream>>>(hs, W, fb, bb, row_ctx, row_tok, hdr, goldv, D2, D);
    final_kernel<<<1, 256, 0, stream>>>(S, goldv, hdr, fhdr, (float*)d_out);
}